// Round 1
// baseline (241.327 us; speedup 1.0000x reference)
//
#include <hip/hip_runtime.h>

// EMA scan: out[:,0,:] = x[:,0,:]; out[:,t,:] = 0.1*x[:,t,:] + 0.9*out[:,t-1,:]
// x: (16, 4096, 512) fp32.
//
// Strategy: chunk the T axis. The recurrence forgets at 0.9^W, so each chunk
// reconstructs its carry with a W=64 warm-up from zero (error <= 0.9^64 * |y|
// ~ 1.6e-3, threshold is 7.6e-2). No inter-block communication needed.
// Each thread owns one float4 column slice of one chunk -> 16B/lane coalesced.

constexpr int B = 16;
constexpr int T = 4096;
constexpr int D = 512;
constexpr int DV = D / 4;      // 128 float4 columns per (b, t) row
constexpr int L = 256;         // chunk length along T
constexpr int C = T / L;       // 16 chunks
constexpr int W = 64;          // warm-up steps (0.9^64 ~ 1.2e-3)
constexpr int UNR = 8;         // loads in flight per wave

__global__ __launch_bounds__(64)
void ema_chunked_kernel(const float4* __restrict__ X, float4* __restrict__ O) {
    const int g     = blockIdx.x * 64 + threadIdx.x;
    const int dvec  = g & (DV - 1);          // consecutive within wave -> coalesced
    const int chunk = (g >> 7) & (C - 1);    // DV = 128 = 1<<7
    const int b     = g >> 11;               // DV*C = 2048 = 1<<11

    const float a  = 0.1f;
    const float bb = 0.9f;

    const int base = b * (T * DV) + dvec;    // max ~8.4M float4, fits int
    const int t0   = chunk * L;

    float4 y;
    if (chunk == 0) {
        // y_init = x0: main-loop step at t=0 gives 0.1*x0 + 0.9*x0 = x0 exactly.
        y = X[base];
    } else {
        y = make_float4(0.f, 0.f, 0.f, 0.f);
        const float4* xp = X + base + (t0 - W) * DV;
        for (int tt = 0; tt < W; tt += UNR) {
            float4 v[UNR];
            #pragma unroll
            for (int j = 0; j < UNR; ++j) v[j] = xp[(tt + j) * DV];
            #pragma unroll
            for (int j = 0; j < UNR; ++j) {
                y.x = fmaf(bb, y.x, a * v[j].x);
                y.y = fmaf(bb, y.y, a * v[j].y);
                y.z = fmaf(bb, y.z, a * v[j].z);
                y.w = fmaf(bb, y.w, a * v[j].w);
            }
        }
    }

    const float4* xp = X + base + t0 * DV;
    float4*       op = O + base + t0 * DV;
    for (int tt = 0; tt < L; tt += UNR) {
        float4 v[UNR];
        #pragma unroll
        for (int j = 0; j < UNR; ++j) v[j] = xp[(tt + j) * DV];
        #pragma unroll
        for (int j = 0; j < UNR; ++j) {
            y.x = fmaf(bb, y.x, a * v[j].x);
            y.y = fmaf(bb, y.y, a * v[j].y);
            y.z = fmaf(bb, y.z, a * v[j].z);
            y.w = fmaf(bb, y.w, a * v[j].w);
            op[(tt + j) * DV] = y;
        }
    }
}

extern "C" void kernel_launch(void* const* d_in, const int* in_sizes, int n_in,
                              void* d_out, int out_size, void* d_ws, size_t ws_size,
                              hipStream_t stream) {
    const float4* X = (const float4*)d_in[0];
    float4*       O = (float4*)d_out;

    const int total_threads = B * C * DV;    // 32768
    const int block = 64;
    const int grid  = total_threads / block; // 512 blocks -> 2 waves/CU
    ema_chunked_kernel<<<grid, block, 0, stream>>>(X, O);
}